// Round 5
// baseline (5523.165 us; speedup 1.0000x reference)
//
#include <hip/hip_runtime.h>

typedef __attribute__((ext_vector_type(8))) short short8v;
typedef __attribute__((ext_vector_type(4))) short short4v;
typedef __attribute__((ext_vector_type(4))) float f32x4;
typedef __attribute__((ext_vector_type(4))) float float4v;
typedef __attribute__((ext_vector_type(4))) unsigned uint4v;
typedef unsigned long long u64;

#define NHID 1024
#define NCAT 1024
#define NB   64
#define NT   512

__device__ __forceinline__ short f2bf(float f) {
  union { float f; unsigned u; } c; c.f = f;
  unsigned r = (c.u + 0x7fffu + ((c.u >> 16) & 1u)) >> 16;
  return (short)r;
}

// x: f32 -> bf16 (xb). h0: f32 -> tagged u32 (tag=0 in hi16) into hb0.
__global__ void cast_kernel(const float* __restrict__ x, const float* __restrict__ h0,
                            short* __restrict__ xb, unsigned* __restrict__ hb0) {
  const long NX4 = (long)NB * NT * NCAT / 4;
  const long NH4 = (long)NB * NHID / 4;
  long i = (long)blockIdx.x * blockDim.x + threadIdx.x;
  long stride = (long)gridDim.x * blockDim.x;
  for (long j = i; j < NX4 + NH4; j += stride) {
    if (j < NH4) {
      float4v v = ((const float4v*)h0)[j];
      uint4v s;
      s[0] = (unsigned short)f2bf(v[0]); s[1] = (unsigned short)f2bf(v[1]);
      s[2] = (unsigned short)f2bf(v[2]); s[3] = (unsigned short)f2bf(v[3]);
      ((uint4v*)hb0)[j] = s;
    } else {
      long jj = j - NH4;
      float4v v = ((const float4v*)x)[jj];
      short4v s; s[0]=f2bf(v[0]); s[1]=f2bf(v[1]); s[2]=f2bf(v[2]); s[3]=f2bf(v[3]);
      ((short4v*)xb)[jj] = s;
    }
  }
}

// 256 persistent wgs x 256 threads; wg=(mt,cg) owns h-tile rows mt*16.. x cols cg*16..
// Protocol: h lives as tagged u32 (hi16=step tag, lo16=bf16). Producers (wave 0)
// repack tile via LDS and publish 128 u64 agent-atomic (write-through) stores;
// the tag travels atomically with the data -> no flags, no fences, no vmcnt drain.
// Consumers (waves 0,1) issue all tagged u64 bypass loads and retry until tag==t.
// L2 is never invalidated: x/weights stay cached. One barrier per step (reduce).
__global__ __launch_bounds__(256, 1) void gru_kernel(
    const float* __restrict__ h0, const float* __restrict__ Wh, const float* __restrict__ Wz,
    const float* __restrict__ Uh, const float* __restrict__ Uz, const float* __restrict__ bz,
    const float* __restrict__ Wout, const short* __restrict__ xb,
    unsigned* __restrict__ hbuf0, unsigned* __restrict__ hbuf1,
    float* __restrict__ out)
{
  extern __shared__ char smem[];
  short8v* ufr = (short8v*)smem;                    // weight B-frags, 128 KB
  float*   red = (float*)(smem + 131072);           // reduce slots [par][3][64][8], 12 KB
  unsigned* rp = (unsigned*)(smem + 131072 + 12288); // wave0 repack tile, 1 KB

  const int tid  = threadIdx.x;
  const int lane = tid & 63;
  const int wv   = tid >> 6;
  const int mt   = blockIdx.x >> 6;
  const int cg   = blockIdx.x & 63;
  const int col  = lane & 15;
  const int quad = lane >> 4;
  const int kq   = quad * 8;
  const int jg   = cg * 16 + col;

  // ---- one-time: weight B-fragments into LDS (16 cols x K=2048 x 2 gates) ----
  for (int idx = tid; idx < 64 * 2 * 64; idx += 256) {
    int l  = idx & 63;
    int nt = (idx >> 6) & 1;
    int kb = idx >> 7;
    int j  = cg * 16 + (l & 15);
    int k0 = (kb & 31) * 32 + (l >> 4) * 8;
    const float* M = (kb < 32) ? (nt ? Uh : Uz) : (nt ? Wh : Wz);
    short8v v;
#pragma unroll
    for (int e = 0; e < 8; ++e) v[e] = f2bf(M[j * 1024 + k0 + e]);
    ufr[idx] = v;
  }
  __syncthreads();

  float hl[4] = {0.f, 0.f, 0.f, 0.f};
  float bzv = 0.f;
  if (wv == 0) {
    bzv = bz[jg];
#pragma unroll
    for (int r = 0; r < 4; ++r) hl[r] = h0[(mt * 16 + quad * 4 + r) * NHID + jg];
  }

  unsigned* hb[2] = { hbuf0, hbuf1 };
  const int kb0 = wv * 16;   // wave k-range (kb units of 32): wv0,1 = h; wv2,3 = x

  short8v xf[16];
  if (wv >= 2) {             // preload x for t=0 (plain loads, L2-cached)
    const short* xrow = xb + ((long)(mt * 16 + col) * NT + 0) * NCAT + (kb0 - 32) * 32 + kq;
#pragma unroll
    for (int i = 0; i < 16; ++i) xf[i] = *(const short8v*)(xrow + i * 32);
  }

  for (int t = 0; t < NT; ++t) {
    const int par = t & 1;
    f32x4 pz = {0.f,0.f,0.f,0.f}, ph = {0.f,0.f,0.f,0.f};

    if (wv < 2) {
      // ---- tagged h consume: retry bypass loads until tag == t ----
      const unsigned tt = (unsigned)t;
      const u64* hq = (const u64*)hb[t & 1] + (mt * 16 + col) * 512 + kb0 * 16 + quad * 4;
      u64 q[64];
      for (;;) {
#pragma unroll
        for (int i = 0; i < 16; ++i)
#pragma unroll
          for (int j = 0; j < 4; ++j)
            q[i * 4 + j] = __hip_atomic_load(hq + i * 16 + j,
                                             __ATOMIC_RELAXED, __HIP_MEMORY_SCOPE_AGENT);
        unsigned bad = 0;
#pragma unroll
        for (int i = 0; i < 64; ++i) bad |= ((unsigned)(q[i] >> 48)) ^ tt;
        if (__ballot(bad != 0) == 0ull) break;
      }
#pragma unroll
      for (int i = 0; i < 16; ++i) {
        short8v a;
#pragma unroll
        for (int j = 0; j < 4; ++j) {
          u64 w = q[i * 4 + j];
          a[2 * j]     = (short)(w & 0xFFFFu);
          a[2 * j + 1] = (short)((w >> 32) & 0xFFFFu);
        }
        int kb = kb0 + i;
        pz = __builtin_amdgcn_mfma_f32_16x16x32_bf16(a, ufr[kb * 128 + lane],      pz, 0, 0, 0);
        ph = __builtin_amdgcn_mfma_f32_16x16x32_bf16(a, ufr[kb * 128 + 64 + lane], ph, 0, 0, 0);
      }
    } else {
#pragma unroll
      for (int i = 0; i < 16; ++i) {
        int kb = kb0 + i;
        pz = __builtin_amdgcn_mfma_f32_16x16x32_bf16(xf[i], ufr[kb * 128 + lane],      pz, 0, 0, 0);
        ph = __builtin_amdgcn_mfma_f32_16x16x32_bf16(xf[i], ufr[kb * 128 + 64 + lane], ph, 0, 0, 0);
      }
      if (t + 1 < NT) {  // prefetch next step's x; completes during barrier wait (L2 hit)
        const short* xrow = xb + ((long)(mt * 16 + col) * NT + (t + 1)) * NCAT + (kb0 - 32) * 32 + kq;
#pragma unroll
        for (int i = 0; i < 16; ++i) xf[i] = *(const short8v*)(xrow + i * 32);
      }
    }

    if (wv != 0) {
      float* sl = red + ((par * 3 + (wv - 1)) * 64 + lane) * 8;
      *(f32x4*)sl       = pz;
      *(f32x4*)(sl + 4) = ph;
    }
    __syncthreads();

    if (wv == 0) {
      f32x4 accz = pz, acch = ph;
#pragma unroll
      for (int s = 0; s < 3; ++s) {
        const float* sl = red + ((par * 3 + s) * 64 + lane) * 8;
        accz += *(const f32x4*)sl;
        acch += *(const f32x4*)(sl + 4);
      }
      // epilogue -> tagged tile in LDS (tag = t+1)
      const unsigned tg = ((unsigned)(t + 1)) << 16;
#pragma unroll
      for (int r = 0; r < 4; ++r) {
        float zp = accz[r] + bzv;
        float z  = 1.f / (1.f + __expf(-zp));
        float ht = tanhf(acch[r]);
        float v  = hl[r] + z * (ht - hl[r]);
        hl[r] = v;
        rp[(quad * 4 + r) * 16 + col] = tg | (unsigned short)f2bf(v);
      }
      __asm__ volatile("s_waitcnt lgkmcnt(0)" ::: "memory");
      // publish: 2 line-aligned u64 write-through stores per lane (128 total)
      u64* hnq = (u64*)hb[(t + 1) & 1];
#pragma unroll
      for (int s2 = 0; s2 < 2; ++s2) {
        int qi  = lane + s2 * 64;
        int row = qi >> 3, qc = qi & 7;
        u64 val = ((const u64*)rp)[qi];
        __hip_atomic_store(hnq + (mt * 16 + row) * 512 + cg * 8 + qc, val,
                           __ATOMIC_RELAXED, __HIP_MEMORY_SCOPE_AGENT);
      }
    }
  }

  // ---- tail: out = hT @ Wout.T, hT = tagged hb[0] (tag NT). k-split 256/wave ----
  {
    const unsigned tt = (unsigned)NT;
    const int kb0t = wv * 8;
    const u64* hq = (const u64*)hbuf0 + (mt * 16 + col) * 512 + kb0t * 16 + quad * 4;
    u64 q[32];
    for (;;) {
#pragma unroll
      for (int i = 0; i < 8; ++i)
#pragma unroll
        for (int j = 0; j < 4; ++j)
          q[i * 4 + j] = __hip_atomic_load(hq + i * 16 + j,
                                           __ATOMIC_RELAXED, __HIP_MEMORY_SCOPE_AGENT);
      unsigned bad = 0;
#pragma unroll
      for (int i = 0; i < 32; ++i) bad |= ((unsigned)(q[i] >> 48)) ^ tt;
      if (__ballot(bad != 0) == 0ull) break;
    }
    f32x4 acc = {0.f,0.f,0.f,0.f};
    const float* wrow = Wout + (long)jg * NHID + kb0t * 32 + kq;
#pragma unroll
    for (int kb = 0; kb < 8; ++kb) {
      short8v a;
#pragma unroll
      for (int j = 0; j < 4; ++j) {
        u64 w = q[kb * 4 + j];
        a[2 * j]     = (short)(w & 0xFFFFu);
        a[2 * j + 1] = (short)((w >> 32) & 0xFFFFu);
      }
      float4v w0 = *(const float4v*)(wrow + kb * 32);
      float4v w1 = *(const float4v*)(wrow + kb * 32 + 4);
      short8v b;
      b[0] = f2bf(w0[0]); b[1] = f2bf(w0[1]); b[2] = f2bf(w0[2]); b[3] = f2bf(w0[3]);
      b[4] = f2bf(w1[0]); b[5] = f2bf(w1[1]); b[6] = f2bf(w1[2]); b[7] = f2bf(w1[3]);
      acc = __builtin_amdgcn_mfma_f32_16x16x32_bf16(a, b, acc, 0, 0, 0);
    }
    if (wv != 0)
      *(f32x4*)(red + ((wv - 1) * 64 + lane) * 8) = acc;
    __syncthreads();
    if (wv == 0) {
#pragma unroll
      for (int s = 0; s < 3; ++s)
        acc += *(const f32x4*)(red + (s * 64 + lane) * 8);
#pragma unroll
      for (int r = 0; r < 4; ++r)
        out[(mt * 16 + quad * 4 + r) * NCAT + jg] = acc[r];
    }
  }
}

extern "C" void kernel_launch(void* const* d_in, const int* in_sizes, int n_in,
                              void* d_out, int out_size, void* d_ws, size_t ws_size,
                              hipStream_t stream) {
  const float* x    = (const float*)d_in[0];
  const float* h0   = (const float*)d_in[1];
  const float* Wh   = (const float*)d_in[2];
  const float* Wz   = (const float*)d_in[3];
  const float* Uh   = (const float*)d_in[5];
  const float* Uz   = (const float*)d_in[6];
  const float* bz   = (const float*)d_in[8];
  const float* Wout = (const float*)d_in[10];

  char* ws = (char*)d_ws;
  // layout: hb0 tagged 256K | hb1 tagged 256K | xb bf16 64MB
  unsigned* hb0 = (unsigned*)ws;
  unsigned* hb1 = (unsigned*)(ws + 262144);
  short*    xb  = (short*)(ws + 524288);

  cast_kernel<<<4096, 256, 0, stream>>>(x, h0, xb, hb0);

  hipFuncSetAttribute((const void*)gru_kernel,
                      hipFuncAttributeMaxDynamicSharedMemorySize, 144384);
  gru_kernel<<<256, 256, 144384, stream>>>(h0, Wh, Wz, Uh, Uz, bz, Wout, xb,
                                           hb0, hb1, (float*)d_out);
}

// Round 6
// 2679.348 us; speedup vs baseline: 2.0614x; 2.0614x over previous
//
#include <hip/hip_runtime.h>

typedef __attribute__((ext_vector_type(8))) short short8v;
typedef __attribute__((ext_vector_type(4))) short short4v;
typedef __attribute__((ext_vector_type(4))) float f32x4;
typedef __attribute__((ext_vector_type(4))) float float4v;
typedef unsigned long long u64;

#define NHID 1024
#define NCAT 1024
#define NB   64
#define NT   512

__device__ __forceinline__ short f2bf(float f) {
  union { float f; unsigned u; } c; c.f = f;
  unsigned r = (c.u + 0x7fffu + ((c.u >> 16) & 1u)) >> 16;
  return (short)r;
}

union HF { u64 q[2]; short8v v; };

__device__ __forceinline__ u64 ald(const u64* p) {   // MALL bypass load
  return __hip_atomic_load(p, __ATOMIC_RELAXED, __HIP_MEMORY_SCOPE_AGENT);
}
__device__ __forceinline__ void ast(u64* p, u64 v) { // MALL write-through store
  __hip_atomic_store(p, v, __ATOMIC_RELAXED, __HIP_MEMORY_SCOPE_AGENT);
}

__global__ void cast_kernel(const float* __restrict__ x, const float* __restrict__ h0,
                            short* __restrict__ xb, short* __restrict__ hb0) {
  const long NX4 = (long)NB * NT * NCAT / 4;
  const long NH4 = (long)NB * NHID / 4;
  long i = (long)blockIdx.x * blockDim.x + threadIdx.x;
  long stride = (long)gridDim.x * blockDim.x;
  for (long j = i; j < NX4 + NH4; j += stride) {
    if (j < NH4) {
      float4v v = ((const float4v*)h0)[j];
      short4v s; s[0]=f2bf(v[0]); s[1]=f2bf(v[1]); s[2]=f2bf(v[2]); s[3]=f2bf(v[3]);
      ((short4v*)hb0)[j] = s;
    } else {
      long jj = j - NH4;
      float4v v = ((const float4v*)x)[jj];
      short4v s; s[0]=f2bf(v[0]); s[1]=f2bf(v[1]); s[2]=f2bf(v[2]); s[3]=f2bf(v[3]);
      ((short4v*)xb)[jj] = s;
    }
  }
}

// 256 persistent wgs x 256 threads; wg=(mt,cg) owns h-tile rows mt*16.. x cols cg*16..
// Flag protocol, fence-free: producer (wave 0) repacks its 512B h-tile in LDS,
// publishes 64 coalesced u64 write-through stores, s_waitcnt vmcnt(0), then one
// u32 flag store (own 64B line). Consumers (waves 0,1) poll ONLY their own
// K-half's 32 producer flags (relaxed, s_sleep backoff), then read h via u64
// bypass loads -> no acquire fence, L2 never invalidated (x/weights stay hot).
// Waves 2,3 handle the x-half off the critical path. One barrier/step (reduce).
__global__ __launch_bounds__(256, 1) void gru_kernel(
    const float* __restrict__ h0, const float* __restrict__ Wh, const float* __restrict__ Wz,
    const float* __restrict__ Uh, const float* __restrict__ Uz, const float* __restrict__ bz,
    const float* __restrict__ Wout, const short* __restrict__ xb,
    short* __restrict__ hbuf0, short* __restrict__ hbuf1,
    unsigned* __restrict__ flags, float* __restrict__ out)
{
  extern __shared__ char smem[];
  short8v* ufr = (short8v*)smem;                     // weight B-frags, 128 KB
  float*   red = (float*)(smem + 131072);            // reduce slots [par][3][64][8], 12 KB
  short*   rp  = (short*)(smem + 131072 + 12288);    // wave0 repack tile, 512 B

  const int tid  = threadIdx.x;
  const int lane = tid & 63;
  const int wv   = tid >> 6;
  const int mt   = blockIdx.x >> 6;
  const int cg   = blockIdx.x & 63;
  const int col  = lane & 15;
  const int quad = lane >> 4;
  const int kq   = quad * 8;
  const int jg   = cg * 16 + col;

  // ---- one-time: weight B-fragments into LDS (16 cols x K=2048 x 2 gates) ----
  for (int idx = tid; idx < 64 * 2 * 64; idx += 256) {
    int l  = idx & 63;
    int nt = (idx >> 6) & 1;
    int kb = idx >> 7;
    int j  = cg * 16 + (l & 15);
    int k0 = (kb & 31) * 32 + (l >> 4) * 8;
    const float* M = (kb < 32) ? (nt ? Uh : Uz) : (nt ? Wh : Wz);
    short8v v;
#pragma unroll
    for (int e = 0; e < 8; ++e) v[e] = f2bf(M[j * 1024 + k0 + e]);
    ufr[idx] = v;
  }
  __syncthreads();

  float hl[4] = {0.f, 0.f, 0.f, 0.f};
  float bzv = 0.f;
  if (wv == 0) {
    bzv = bz[jg];
#pragma unroll
    for (int r = 0; r < 4; ++r) hl[r] = h0[(mt * 16 + quad * 4 + r) * NHID + jg];
  }

  short* hb[2] = { hbuf0, hbuf1 };
  const int kb0 = wv * 16;   // wave k-range (kb=32-K units): wv0,1 = h; wv2,3 = x
  unsigned* myflag = flags + (mt * 64 + cg) * 16;
  // consumer wave wv<2 polls only its own K-half's producers: cg in [wv*32, wv*32+32)
  const unsigned* pollp  = flags + (mt * 64 + (wv & 1) * 32 + (lane & 31)) * 16;
  // tail: wave wv needs cols [wv*256, wv*256+256) -> producers cg [wv*16, +16)
  const unsigned* pollpt = flags + (mt * 64 + wv * 16 + (lane & 15)) * 16;

  short8v xf[16];
  if (wv >= 2) {             // preload x for t=0 (plain loads, L2-cached)
    const short* xrow = xb + ((long)(mt * 16 + col) * NT + 0) * NCAT + (kb0 - 32) * 32 + kq;
#pragma unroll
    for (int i = 0; i < 16; ++i) xf[i] = *(const short8v*)(xrow + i * 32);
  }

  for (int t = 0; t < NT; ++t) {
    const int par = t & 1;
    f32x4 pz = {0.f,0.f,0.f,0.f}, ph = {0.f,0.f,0.f,0.f};

    if (wv < 2) {
      if (t > 0) {
        const unsigned tt = (unsigned)t;
        for (;;) {
          unsigned v = __hip_atomic_load(pollp, __ATOMIC_RELAXED, __HIP_MEMORY_SCOPE_AGENT);
          if (__ballot(v < tt) == 0ull) break;
          __builtin_amdgcn_s_sleep(1);
        }
      }
      // h row stride = 1024 shorts = 256 u64; kb stride = 32 shorts = 8 u64
      const u64* hq = (const u64*)hb[t & 1] + (mt * 16 + col) * 256 + kb0 * 8 + quad * 2;
      u64 q[32];
#pragma unroll
      for (int i = 0; i < 16; ++i) {
        q[2 * i]     = ald(hq + i * 8);
        q[2 * i + 1] = ald(hq + i * 8 + 1);
      }
#pragma unroll
      for (int i = 0; i < 16; ++i) {
        HF f; f.q[0] = q[2 * i]; f.q[1] = q[2 * i + 1];
        int kb = kb0 + i;
        pz = __builtin_amdgcn_mfma_f32_16x16x32_bf16(f.v, ufr[kb * 128 + lane],      pz, 0, 0, 0);
        ph = __builtin_amdgcn_mfma_f32_16x16x32_bf16(f.v, ufr[kb * 128 + 64 + lane], ph, 0, 0, 0);
      }
    } else {
#pragma unroll
      for (int i = 0; i < 16; ++i) {
        int kb = kb0 + i;
        pz = __builtin_amdgcn_mfma_f32_16x16x32_bf16(xf[i], ufr[kb * 128 + lane],      pz, 0, 0, 0);
        ph = __builtin_amdgcn_mfma_f32_16x16x32_bf16(xf[i], ufr[kb * 128 + 64 + lane], ph, 0, 0, 0);
      }
      if (t + 1 < NT) {  // prefetch next x (L2 hit; completes during barrier wait)
        const short* xrow = xb + ((long)(mt * 16 + col) * NT + (t + 1)) * NCAT + (kb0 - 32) * 32 + kq;
#pragma unroll
        for (int i = 0; i < 16; ++i) xf[i] = *(const short8v*)(xrow + i * 32);
      }
    }

    if (wv != 0) {
      float* sl = red + ((par * 3 + (wv - 1)) * 64 + lane) * 8;
      *(f32x4*)sl       = pz;
      *(f32x4*)(sl + 4) = ph;
    }
    __syncthreads();

    if (wv == 0) {
      f32x4 accz = pz, acch = ph;
#pragma unroll
      for (int s = 0; s < 3; ++s) {
        const float* sl = red + ((par * 3 + s) * 64 + lane) * 8;
        accz += *(const f32x4*)sl;
        acch += *(const f32x4*)(sl + 4);
      }
      // epilogue: z = sigmoid(zp), ht = tanh = 2*sigmoid(2x)-1 (overflow-safe)
#pragma unroll
      for (int r = 0; r < 4; ++r) {
        float zp = accz[r] + bzv;
        float z  = 1.f / (1.f + __expf(-zp));
        float ht = 2.f / (1.f + __expf(-2.f * acch[r])) - 1.f;
        float v  = hl[r] + z * (ht - hl[r]);
        hl[r] = v;
        rp[(quad * 4 + r) * 16 + col] = f2bf(v);    // repack tile in LDS
      }
      __asm__ volatile("s_waitcnt lgkmcnt(0)" ::: "memory");  // wave-internal LDS RAW
      // publish: 1 coalesced u64 per lane (row = lane>>2, 4-u64 row segment)
      u64 val = ((const u64*)rp)[lane];
      u64* hnq = (u64*)hb[(t + 1) & 1];
      ast(hnq + (mt * 16 + (lane >> 2)) * 256 + cg * 4 + (lane & 3), val);
      __asm__ volatile("s_waitcnt vmcnt(0)" ::: "memory");    // tile at coherence point
      if (lane == 0)
        __hip_atomic_store(myflag, (unsigned)(t + 1), __ATOMIC_RELAXED, __HIP_MEMORY_SCOPE_AGENT);
    }
  }

  // ---- tail: out = hT @ Wout.T (hT = hb[0], flag NT). K-split 256/wave ----
  {
    for (;;) {
      unsigned v = __hip_atomic_load(pollpt, __ATOMIC_RELAXED, __HIP_MEMORY_SCOPE_AGENT);
      if (__ballot(v < (unsigned)NT) == 0ull) break;
      __builtin_amdgcn_s_sleep(1);
    }
    const int kb0t = wv * 8;
    const u64* hq = (const u64*)hbuf0 + (mt * 16 + col) * 256 + kb0t * 8 + quad * 2;
    u64 q[16];
#pragma unroll
    for (int i = 0; i < 8; ++i) {
      q[2 * i]     = ald(hq + i * 8);
      q[2 * i + 1] = ald(hq + i * 8 + 1);
    }
    f32x4 acc = {0.f,0.f,0.f,0.f};
    const float* wrow = Wout + (long)jg * NHID + kb0t * 32 + kq;
#pragma unroll
    for (int kb = 0; kb < 8; ++kb) {
      HF f; f.q[0] = q[2 * kb]; f.q[1] = q[2 * kb + 1];
      float4v w0 = *(const float4v*)(wrow + kb * 32);
      float4v w1 = *(const float4v*)(wrow + kb * 32 + 4);
      short8v b;
      b[0] = f2bf(w0[0]); b[1] = f2bf(w0[1]); b[2] = f2bf(w0[2]); b[3] = f2bf(w0[3]);
      b[4] = f2bf(w1[0]); b[5] = f2bf(w1[1]); b[6] = f2bf(w1[2]); b[7] = f2bf(w1[3]);
      acc = __builtin_amdgcn_mfma_f32_16x16x32_bf16(f.v, b, acc, 0, 0, 0);
    }
    if (wv != 0)
      *(f32x4*)(red + ((wv - 1) * 64 + lane) * 8) = acc;
    __syncthreads();
    if (wv == 0) {
#pragma unroll
      for (int s = 0; s < 3; ++s)
        acc += *(const f32x4*)(red + (s * 64 + lane) * 8);
#pragma unroll
      for (int r = 0; r < 4; ++r)
        out[(mt * 16 + quad * 4 + r) * NCAT + jg] = acc[r];
    }
  }
}

extern "C" void kernel_launch(void* const* d_in, const int* in_sizes, int n_in,
                              void* d_out, int out_size, void* d_ws, size_t ws_size,
                              hipStream_t stream) {
  const float* x    = (const float*)d_in[0];
  const float* h0   = (const float*)d_in[1];
  const float* Wh   = (const float*)d_in[2];
  const float* Wz   = (const float*)d_in[3];
  const float* Uh   = (const float*)d_in[5];
  const float* Uz   = (const float*)d_in[6];
  const float* bz   = (const float*)d_in[8];
  const float* Wout = (const float*)d_in[10];

  char* ws = (char*)d_ws;
  // layout: flags [0,16K) (256 wgs x 64B) | hb0 128K | hb1 128K | xb bf16 64MB
  unsigned* flags = (unsigned*)ws;
  short* hb0 = (short*)(ws + 16384);
  short* hb1 = (short*)(ws + 16384 + 131072);
  short* xb  = (short*)(ws + 16384 + 262144);

  hipMemsetAsync(flags, 0, 16384, stream);
  cast_kernel<<<4096, 256, 0, stream>>>(x, h0, xb, hb0);

  hipFuncSetAttribute((const void*)gru_kernel,
                      hipFuncAttributeMaxDynamicSharedMemorySize, 144384);
  gru_kernel<<<256, 256, 144384, stream>>>(h0, Wh, Wz, Uh, Uz, bz, Wout, xb,
                                           hb0, hb1, flags, (float*)d_out);
}

// Round 7
// 2383.618 us; speedup vs baseline: 2.3171x; 1.1241x over previous
//
#include <hip/hip_runtime.h>

typedef __attribute__((ext_vector_type(8))) short short8v;
typedef __attribute__((ext_vector_type(4))) float f32x4;
typedef __attribute__((ext_vector_type(4))) float float4v;
typedef unsigned long long u64;

#define NHID 1024
#define NCAT 1024
#define NB   64
#define NT   512
#define RING_STRIDE 65536   // shorts per ring slot (128 KB)

__device__ __forceinline__ short f2bf(float f) {
  union { float f; unsigned u; } c; c.f = f;
  unsigned r = (c.u + 0x7fffu + ((c.u >> 16) & 1u)) >> 16;
  return (short)r;
}

__device__ __forceinline__ void ast(u64* p, u64 v) { // MALL write-through store
  __hip_atomic_store(p, v, __ATOMIC_RELAXED, __HIP_MEMORY_SCOPE_AGENT);
}

__device__ __forceinline__ short8v cvt8(float4v a, float4v b) {
  short8v s;
  s[0]=f2bf(a[0]); s[1]=f2bf(a[1]); s[2]=f2bf(a[2]); s[3]=f2bf(a[3]);
  s[4]=f2bf(b[0]); s[5]=f2bf(b[1]); s[6]=f2bf(b[2]); s[7]=f2bf(b[3]);
  return s;
}

// 256 persistent wgs x 256 threads; wg=(mt,cg) owns h-tile rows mt*16.. x cols cg*16..
// h lives in a 513-slot ring (slot t = h after t steps): every address is
// produced/consumed exactly once per launch, so consumers use NORMAL cached
// loads (per-XCD L2 serves the 64x h-broadcast amplification); producers
// publish via agent-atomic (L2-bypassing write-through) u64 stores + vmcnt
// drain + per-wg flag on its own 64B line. One acquire fence at kernel entry
// kills cross-launch stale lines; none per step -> x/weights stay L2-hot.
// Waves 0,1 = h-half of K (critical path); waves 2,3 = x-half (read x fp32
// directly, convert in-register, prefetch next step during barrier wait).
__global__ __launch_bounds__(256, 1) void gru_kernel(
    const float* __restrict__ h0, const float* __restrict__ Wh, const float* __restrict__ Wz,
    const float* __restrict__ Uh, const float* __restrict__ Uz, const float* __restrict__ bz,
    const float* __restrict__ Wout, const float* __restrict__ x,
    short* __restrict__ ring, unsigned* __restrict__ flags, float* __restrict__ out)
{
  extern __shared__ char smem[];
  short8v* ufr = (short8v*)smem;                     // weight B-frags, 128 KB
  float*   red = (float*)(smem + 131072);            // reduce slots [par][3][64][8], 12 KB
  short*   rp  = (short*)(smem + 131072 + 12288);    // wave0 repack tile, 512 B

  // one-time agent acquire: invalidate L1/L2 so cross-launch stale lines die
  __builtin_amdgcn_fence(__ATOMIC_ACQUIRE, "agent");

  const int tid  = threadIdx.x;
  const int lane = tid & 63;
  const int wv   = tid >> 6;
  const int mt   = blockIdx.x >> 6;
  const int cg   = blockIdx.x & 63;
  const int col  = lane & 15;
  const int quad = lane >> 4;
  const int kq   = quad * 8;
  const int jg   = cg * 16 + col;

  // ---- one-time: weight B-fragments into LDS (16 cols x K=2048 x 2 gates) ----
  for (int idx = tid; idx < 64 * 2 * 64; idx += 256) {
    int l  = idx & 63;
    int nt = (idx >> 6) & 1;
    int kb = idx >> 7;
    int j  = cg * 16 + (l & 15);
    int k0 = (kb & 31) * 32 + (l >> 4) * 8;
    const float* M = (kb < 32) ? (nt ? Uh : Uz) : (nt ? Wh : Wz);
    short8v v;
#pragma unroll
    for (int e = 0; e < 8; ++e) v[e] = f2bf(M[j * 1024 + k0 + e]);
    ufr[idx] = v;
  }
  __syncthreads();

  float hl[4] = {0.f, 0.f, 0.f, 0.f};
  float bzv = 0.f;
  if (wv == 0) {
    bzv = bz[jg];
#pragma unroll
    for (int r = 0; r < 4; ++r) hl[r] = h0[(mt * 16 + quad * 4 + r) * NHID + jg];
  }

  const int kb0 = wv * 16;   // wave k-range (kb = 32-K units): wv0,1 = h; wv2,3 = x
  unsigned* myflag = flags + (mt * 64 + cg) * 16;
  // consumer wave wv<2 polls only its K-half's producers: cg in [wv*32, wv*32+32)
  const unsigned* pollp  = flags + (mt * 64 + (wv & 1) * 32 + (lane & 31)) * 16;
  // tail: wave wv needs cols [wv*256, +256) -> producers cg [wv*16, +16)
  const unsigned* pollpt = flags + (mt * 64 + wv * 16 + (lane & 15)) * 16;

  short8v xf[16];
  if (wv >= 2) {             // preload x_0 (fp32 direct, convert in-register)
    const float* xrow = x + ((long)(mt * 16 + col) * NT + 0) * NCAT + (kb0 - 32) * 32 + kq;
#pragma unroll
    for (int i = 0; i < 16; ++i)
      xf[i] = cvt8(*(const float4v*)(xrow + i * 32), *(const float4v*)(xrow + i * 32 + 4));
  }

  for (int t = 0; t < NT; ++t) {
    const int par = t & 1;
    f32x4 pz = {0.f,0.f,0.f,0.f}, ph = {0.f,0.f,0.f,0.f};

    if (wv < 2) {
      short8v f[16];
      if (t > 0) {
        const unsigned tt = (unsigned)t;
        for (;;) {
          unsigned v = __hip_atomic_load(pollp, __ATOMIC_RELAXED, __HIP_MEMORY_SCOPE_AGENT);
          if (__ballot(v < tt) == 0ull) break;
          __builtin_amdgcn_s_sleep(1);
        }
        __asm__ volatile("" ::: "memory");   // keep h loads below poll exit
        const short* hrow = ring + (size_t)t * RING_STRIDE
                          + (mt * 16 + col) * 1024 + kb0 * 32 + kq;
#pragma unroll
        for (int i = 0; i < 16; ++i) f[i] = *(const short8v*)(hrow + i * 32);  // cached
      } else {
        const float* hrow = h0 + (mt * 16 + col) * NHID + kb0 * 32 + kq;
#pragma unroll
        for (int i = 0; i < 16; ++i)
          f[i] = cvt8(*(const float4v*)(hrow + i * 32), *(const float4v*)(hrow + i * 32 + 4));
      }
#pragma unroll
      for (int i = 0; i < 16; ++i) {
        int kb = kb0 + i;
        pz = __builtin_amdgcn_mfma_f32_16x16x32_bf16(f[i], ufr[kb * 128 + lane],      pz, 0, 0, 0);
        ph = __builtin_amdgcn_mfma_f32_16x16x32_bf16(f[i], ufr[kb * 128 + 64 + lane], ph, 0, 0, 0);
      }
    } else {
#pragma unroll
      for (int i = 0; i < 16; ++i) {
        int kb = kb0 + i;
        pz = __builtin_amdgcn_mfma_f32_16x16x32_bf16(xf[i], ufr[kb * 128 + lane],      pz, 0, 0, 0);
        ph = __builtin_amdgcn_mfma_f32_16x16x32_bf16(xf[i], ufr[kb * 128 + 64 + lane], ph, 0, 0, 0);
      }
      if (t + 1 < NT) {  // prefetch next x (L2-hot after first pass; off critical path)
        const float* xrow = x + ((long)(mt * 16 + col) * NT + (t + 1)) * NCAT + (kb0 - 32) * 32 + kq;
#pragma unroll
        for (int i = 0; i < 16; ++i)
          xf[i] = cvt8(*(const float4v*)(xrow + i * 32), *(const float4v*)(xrow + i * 32 + 4));
      }
    }

    if (wv != 0) {
      float* sl = red + ((par * 3 + (wv - 1)) * 64 + lane) * 8;
      *(f32x4*)sl       = pz;
      *(f32x4*)(sl + 4) = ph;
    }
    __syncthreads();

    if (wv == 0) {
      f32x4 accz = pz, acch = ph;
#pragma unroll
      for (int s = 0; s < 3; ++s) {
        const float* sl = red + ((par * 3 + s) * 64 + lane) * 8;
        accz += *(const f32x4*)sl;
        acch += *(const f32x4*)(sl + 4);
      }
      // epilogue: z = sigmoid, ht = tanh via 2*sigmoid(2x)-1 (overflow-safe)
#pragma unroll
      for (int r = 0; r < 4; ++r) {
        float zp = accz[r] + bzv;
        float z  = 1.f / (1.f + __expf(-zp));
        float ht = 2.f / (1.f + __expf(-2.f * acch[r])) - 1.f;
        float v  = hl[r] + z * (ht - hl[r]);
        hl[r] = v;
        rp[(quad * 4 + r) * 16 + col] = f2bf(v);
      }
      __asm__ volatile("s_waitcnt lgkmcnt(0)" ::: "memory");   // wave-internal LDS RAW
      // publish: 1 coalesced u64 per lane into fresh ring slot t+1
      u64 val = ((const u64*)rp)[lane];
      u64* hnq = (u64*)(ring + (size_t)(t + 1) * RING_STRIDE);
      ast(hnq + (mt * 16 + (lane >> 2)) * 256 + cg * 4 + (lane & 3), val);
      __asm__ volatile("s_waitcnt vmcnt(0)" ::: "memory");     // tile at coherence point
      if (lane == 0)
        __hip_atomic_store(myflag, (unsigned)(t + 1), __ATOMIC_RELAXED, __HIP_MEMORY_SCOPE_AGENT);
    }
  }

  // ---- tail: out = hT @ Wout.T (hT = ring[NT], flag NT). K-split 256/wave ----
  {
    for (;;) {
      unsigned v = __hip_atomic_load(pollpt, __ATOMIC_RELAXED, __HIP_MEMORY_SCOPE_AGENT);
      if (__ballot(v < (unsigned)NT) == 0ull) break;
      __builtin_amdgcn_s_sleep(1);
    }
    __asm__ volatile("" ::: "memory");
    const int kb0t = wv * 8;
    const short* hrow = ring + (size_t)NT * RING_STRIDE
                      + (mt * 16 + col) * 1024 + kb0t * 32 + kq;
    f32x4 acc = {0.f,0.f,0.f,0.f};
    const float* wrow = Wout + (long)jg * NHID + kb0t * 32 + kq;
#pragma unroll
    for (int kb = 0; kb < 8; ++kb) {
      short8v a = *(const short8v*)(hrow + kb * 32);
      float4v w0 = *(const float4v*)(wrow + kb * 32);
      float4v w1 = *(const float4v*)(wrow + kb * 32 + 4);
      acc = __builtin_amdgcn_mfma_f32_16x16x32_bf16(a, cvt8(w0, w1), acc, 0, 0, 0);
    }
    if (wv != 0)
      *(f32x4*)(red + ((wv - 1) * 64 + lane) * 8) = acc;
    __syncthreads();
    if (wv == 0) {
#pragma unroll
      for (int s = 0; s < 3; ++s)
        acc += *(const f32x4*)(red + (s * 64 + lane) * 8);
#pragma unroll
      for (int r = 0; r < 4; ++r)
        out[(mt * 16 + quad * 4 + r) * NCAT + jg] = acc[r];
    }
  }
}

extern "C" void kernel_launch(void* const* d_in, const int* in_sizes, int n_in,
                              void* d_out, int out_size, void* d_ws, size_t ws_size,
                              hipStream_t stream) {
  const float* x    = (const float*)d_in[0];
  const float* h0   = (const float*)d_in[1];
  const float* Wh   = (const float*)d_in[2];
  const float* Wz   = (const float*)d_in[3];
  const float* Uh   = (const float*)d_in[5];
  const float* Uz   = (const float*)d_in[6];
  const float* bz   = (const float*)d_in[8];
  const float* Wout = (const float*)d_in[10];

  char* ws = (char*)d_ws;
  // layout: flags [0,16K) (256 wgs x 64B) | h-ring 513 x 128K = 64.1 MB
  unsigned* flags = (unsigned*)ws;
  short* ring = (short*)(ws + 16384);

  hipMemsetAsync(flags, 0, 16384, stream);

  hipFuncSetAttribute((const void*)gru_kernel,
                      hipFuncAttributeMaxDynamicSharedMemorySize, 143872);
  gru_kernel<<<256, 256, 143872, stream>>>(h0, Wh, Wz, Uh, Uz, bz, Wout, x,
                                           ring, flags, (float*)d_out);
}